// Round 7
// baseline (463.425 us; speedup 1.0000x reference)
//
#include <hip/hip_runtime.h>
#include <hip/hip_cooperative_groups.h>
#include <stdint.h>

#pragma clang fp contract(off)

#define B_ 2
#define P_ 512
#define C_ 21
#define CF 20            // foreground classes
#define G_ (B_ * CF)     // 40 groups
#define DET 100
#define SCORE_THRESH 0.05f
#define NMS_THR 0.5f
#define BBOX_CLIP 4.135166556742356f   // log(1000/16)
#define NC (CF * DET)    // 2000 candidates per image
#define GRID 256
#define TPB 256

typedef unsigned long long u64;
typedef unsigned int u32;

namespace cg = cooperative_groups;

__device__ __forceinline__ u32 f2o(float f) {
  u32 u = __float_as_uint(f);
  return (u & 0x80000000u) ? ~u : (u | 0x80000000u);
}
__device__ __forceinline__ float o2f(u32 o) {
  u32 u = (o & 0x80000000u) ? (o ^ 0x80000000u) : ~o;
  return __uint_as_float(u);
}

// ---------------------------------------------------------------------------
// exact convex quad-quad intersection area — register-resident, bit-identical
// float op order vs reference (fp contract off). Clips quad q by edges of r.
// ---------------------------------------------------------------------------
__device__ __forceinline__ float inter_area_reg(const float qx[4], const float qy[4],
                                                const float rx[4], const float ry[4]) {
  float px_[8], py_[8];
  #pragma unroll
  for (int t = 0; t < 8; ++t) { px_[t] = (t < 4) ? qx[t] : 0.f; py_[t] = (t < 4) ? qy[t] : 0.f; }
  int n = 4;
  #pragma unroll
  for (int e = 0; e < 4; ++e) {
    float a0 = rx[e], a1 = ry[e];
    float b0 = rx[(e + 1) & 3], b1 = ry[(e + 1) & 3];
    float dx = b0 - a0, dy = b1 - a1;
    float ox_[8], oy_[8];
    #pragma unroll
    for (int t = 0; t < 8; ++t) { ox_[t] = 0.f; oy_[t] = 0.f; }
    float cr[8];
    #pragma unroll
    for (int t = 0; t < 8; ++t) cr[t] = dx * (py_[t] - a1) - dy * (px_[t] - a0);
    int m = 0;
    int nn = (n > 1) ? n : 1;
    #pragma unroll
    for (int t = 0; t < 8; ++t) {
      bool act = t < n;
      float sx = px_[t], sy = py_[t];
      float ex, ey, ce;
      if (t == 7) { ex = px_[0]; ey = py_[0]; ce = cr[0]; }
      else {
        bool wrap = (t + 1 == nn);
        ex = wrap ? px_[0] : px_[t + 1];
        ey = wrap ? py_[0] : py_[t + 1];
        ce = wrap ? cr[0] : cr[t + 1];
      }
      float cs = cr[t];
      float denom = cs - ce;
      float dn = (fabsf(denom) > 1e-12f) ? denom : 1e-12f;
      float tt = cs / dn;
      float ipx = sx + tt * (ex - sx);
      float ipy = sy + tt * (ey - sy);
      bool s_in = cs >= 0.f, e_in = ce >= 0.f;
      bool app1 = act && (s_in != e_in);
      #pragma unroll
      for (int s2 = 0; s2 < 8; ++s2) {
        bool wr = app1 && (m == s2);
        ox_[s2] = wr ? ipx : ox_[s2];
        oy_[s2] = wr ? ipy : oy_[s2];
      }
      m += app1 ? 1 : 0;
      bool app2 = act && e_in;
      #pragma unroll
      for (int s2 = 0; s2 < 8; ++s2) {
        bool wr = app2 && (m == s2);
        ox_[s2] = wr ? ex : ox_[s2];
        oy_[s2] = wr ? ey : oy_[s2];
      }
      m += app2 ? 1 : 0;
    }
    n = m;
    #pragma unroll
    for (int t = 0; t < 8; ++t) { px_[t] = ox_[t]; py_[t] = oy_[t]; }
  }
  int nn = (n > 1) ? n : 1;
  float s = 0.f;
  #pragma unroll
  for (int t = 0; t < 8; ++t) {
    if (t < n) {
      float nx_x, nx_y;
      if (t == 7) { nx_x = px_[0]; nx_y = py_[0]; }
      else {
        bool wrap = (t + 1 == nn);
        nx_x = wrap ? px_[0] : px_[t + 1];
        nx_y = wrap ? py_[0] : py_[t + 1];
      }
      s += px_[t] * nx_y - nx_x * py_[t];
    }
  }
  float area = 0.5f * fabsf(s);
  return (n >= 3) ? area : 0.f;
}

// ---------------------------------------------------------------------------
// Fused cooperative kernel: decode -> rank-sort -> pairs -> greedy -> topk.
// grid 256 x 256, grid.sync() between phases. LDS reused as a union (~33 KB).
// ---------------------------------------------------------------------------
__global__ void __launch_bounds__(256, 1)
fused_kernel(const float* __restrict__ logits,
             const float* __restrict__ breg,
             const float* __restrict__ rrects,
             u64* __restrict__ lkeyG,    // [G*P] unsorted keys
             float* __restrict__ scsS,   // [G*P] sorted scores (valid prefix)
             float* __restrict__ ptsS,   // [G*P][8] sorted pts
             float* __restrict__ aabbS,  // [G*P][4] sorted unclipped aabb
             float* __restrict__ pr5S,   // [G*P][5] sorted proposals
             float* __restrict__ areaS,  // [G*P] sorted area
             int* __restrict__ gV,
             u64* __restrict__ sup,      // [G*P][8] suppression bitrows
             u64* __restrict__ cand,     // [G*DET] keys
             float* __restrict__ rec,    // [G*DET][12]
             float* __restrict__ out) {
  cg::grid_group grid = cg::this_grid();
  int tid = threadIdx.x;
  int gid = blockIdx.x * TPB + tid;

  __shared__ u64 shbuf[P_ * 8 + 16];    // 32 KB + slack, aliased per phase

  // ===== Phase 1: zero sup (all threads) + decode (first 20480 threads) ====
  for (int w = gid; w < G_ * P_ * 8; w += GRID * TPB) sup[w] = 0ull;

  float fx[4], fy[4], fab[4], fp5[5], farea = 0.f, fsc = -1.0f;
  u64 mykey = 0;
  int g = 0, p = 0;
  bool active = gid < G_ * P_;
  if (active) {
    g = gid >> 9; p = gid & (P_ - 1);
    int b = g / CF, cf = g % CF, c = cf + 1;
    int n = b * P_ + p;
    const float* lg = logits + n * C_;
    float mx = lg[0];
    for (int k = 1; k < C_; ++k) mx = fmaxf(mx, lg[k]);
    float den = 0.f;
    for (int k = 0; k < C_; ++k) den += expf(lg[k] - mx);
    float sc = expf(lg[c] - mx) / den;

    const float* d = breg + n * (C_ * 5) + c * 5;
    float dxx = d[0] / 10.0f, dyy = d[1] / 10.0f;
    float dw = d[2] / 5.0f, dh = d[3] / 5.0f, da = d[4] / 3.0f;
    dw = fminf(dw, BBOX_CLIP);
    dh = fminf(dh, BBOX_CLIP);
    const float* an = rrects + n * 5;
    float px = dxx * an[2] + an[0];
    float py = dyy * an[3] + an[1];
    float pw = expf(dw) * an[2];
    float ph = expf(dh) * an[3];
    float pa = da * 57.29577951308232f + an[4];
    fp5[0] = px; fp5[1] = py; fp5[2] = pw; fp5[3] = ph; fp5[4] = pa;
    farea = pw * ph;

    float t = pa * 0.017453292519943295f;
    float cs = cosf(t), sn = sinf(t);
    float hx = pw * 0.5f, hy = ph * 0.5f;
    float ox[4] = {-hx, hx, hx, -hx};
    float oy[4] = {-hy, -hy, hy, hy};
    float minx = 1e30f, miny = 1e30f, maxx = -1e30f, maxy = -1e30f;
    #pragma unroll
    for (int qq = 0; qq < 4; ++qq) {
      float x = px + cs * ox[qq] - sn * oy[qq];
      float y = py + sn * ox[qq] + cs * oy[qq];
      fx[qq] = x; fy[qq] = y;
      minx = fminf(minx, x); maxx = fmaxf(maxx, x);
      miny = fminf(miny, y); maxy = fmaxf(maxy, y);
    }
    fab[0] = minx; fab[1] = miny; fab[2] = maxx; fab[3] = maxy;

    bool valid = sc > SCORE_THRESH;
    fsc = valid ? sc : -1.0f;
    mykey = ((u64)f2o(fsc) << 32) | (u32)(~(u32)p);
    lkeyG[gid] = mykey;
  }
  __threadfence();
  grid.sync();

  // ===== Phase 2: per-group rank (LDS keys) + scatter sorted payload =======
  if (blockIdx.x < (G_ * P_) / TPB) {   // 80 blocks; each touches ONE group
    u64* keys = shbuf;
    int g2 = (blockIdx.x * TPB) >> 9;
    for (int i = tid; i < P_; i += TPB) keys[i] = lkeyG[g2 * P_ + i];
    __syncthreads();
    u64 k = mykey;
    int rank = 0, V = 0;
    for (int s = 0; s < P_; ++s) {
      u64 ks = keys[s];
      rank += (ks > k) ? 1 : 0;
      V += ((u32)(ks >> 32) > 0x80000000u) ? 1 : 0;   // score > 0
    }
    if (p == 0) gV[g] = V;
    if (fsc > 0.f) {
      int so = g * P_ + rank;
      scsS[so] = fsc;
      ((float4*)ptsS)[so * 2]     = make_float4(fx[0], fx[1], fx[2], fx[3]);
      ((float4*)ptsS)[so * 2 + 1] = make_float4(fy[0], fy[1], fy[2], fy[3]);
      ((float4*)aabbS)[so] = make_float4(fab[0], fab[1], fab[2], fab[3]);
      pr5S[so * 5 + 0] = fp5[0]; pr5S[so * 5 + 1] = fp5[1];
      pr5S[so * 5 + 2] = fp5[2]; pr5S[so * 5 + 3] = fp5[3];
      pr5S[so * 5 + 4] = fp5[4];
      areaS[so] = farea;
    }
  }
  __threadfence();
  grid.sync();

  // ===== Phase 3: pairwise suppression (AABB reject -> LDS queue -> clip) ==
  {
    u32* q = (u32*)shbuf;                 // 1024 entries
    int* qn = (int*)(shbuf + 512);
    const float4* ab = (const float4*)aabbS;
    const float4* pS = (const float4*)ptsS;
    for (int u = blockIdx.x; u < G_ * 128; u += GRID) {
      int g3 = u >> 7, cch = u & 127;
      int V = gV[g3];
      int Tp = V * (V - 1) / 2;
      int base = cch * 1024;
      if (base >= Tp) continue;
      if (tid == 0) *qn = 0;
      __syncthreads();
      #pragma unroll
      for (int t = 0; t < 4; ++t) {
        int kk = base + t * TPB + tid;
        if (kk >= Tp) break;
        float kf = (float)kk;
        int i = (int)((1.0f + sqrtf(1.0f + 8.0f * kf)) * 0.5f);
        while (i * (i - 1) / 2 > kk) --i;
        while ((i + 1) * i / 2 <= kk) ++i;
        int j = kk - i * (i - 1) / 2;
        float4 bi = ab[g3 * P_ + i];
        float4 bj = ab[g3 * P_ + j];
        bool ov = (bi.x <= bj.z) && (bj.x <= bi.z) && (bi.y <= bj.w) && (bj.y <= bi.w);
        if (ov) {
          int s = atomicAdd(qn, 1);
          q[s] = (u32)((i << 9) | j);
        }
      }
      __syncthreads();
      int nq = *qn;
      for (int s = tid; s < nq; s += TPB) {
        u32 pk = q[s];
        int i = (int)(pk >> 9), j = (int)(pk & 511);
        float4 ax = pS[(g3 * P_ + i) * 2];
        float4 ay = pS[(g3 * P_ + i) * 2 + 1];
        float4 bx = pS[(g3 * P_ + j) * 2];
        float4 by = pS[(g3 * P_ + j) * 2 + 1];
        float qx[4] = {ax.x, ax.y, ax.z, ax.w};
        float qy[4] = {ay.x, ay.y, ay.z, ay.w};
        float rx[4] = {bx.x, bx.y, bx.z, bx.w};
        float ry[4] = {by.x, by.y, by.z, by.w};
        float ai = areaS[g3 * P_ + i];
        float aj = areaS[g3 * P_ + j];
        // reference iou[i][j]: clip quad i by edges of quad j
        float inter = inter_area_reg(qx, qy, rx, ry);
        float iou = inter / (((ai + aj) - inter) + 1e-8f);
        if (iou > NMS_THR)
          atomicOr(&sup[((size_t)g3 * P_ + i) * 8 + (j >> 6)], 1ull << (j & 63));
      }
      __syncthreads();
    }
  }
  __threadfence();
  grid.sync();

  // ===== Phase 4: per-group greedy (blocks 0..39) + emit key/record ========
  if (blockIdx.x < G_) {
    u64* lsup = shbuf;                       // 512*8 u64 = 32 KB
    u32* skeep = (u32*)(shbuf + P_ * 8);     // 16 u32
    int g4 = blockIdx.x;
    int V = gV[g4];
    for (int w = tid; w < V * 8; w += TPB) lsup[w] = sup[(size_t)g4 * P_ * 8 + w];
    __syncthreads();
    if (tid < 64) {
      u64 keepw = 0;
      u64 cur = (tid < 8 && V > 0) ? lsup[tid] : 0ull;
      for (int i = 0; i < V; ++i) {
        u64 nxt = (tid < 8 && (i + 1) < V) ? lsup[(i + 1) * 8 + tid] : 0ull;
        bool supd = __any((cur & keepw) != 0ull);
        if (!supd && tid == (i >> 6)) keepw |= 1ull << (i & 63);
        cur = nxt;
      }
      if (tid < 8) { skeep[tid * 2] = (u32)keepw; skeep[tid * 2 + 1] = (u32)(keepw >> 32); }
    }
    __syncthreads();
    int cls = g4 % CF;
    int tot = 0;
    #pragma unroll
    for (int t = 0; t < 16; ++t) tot += __popc(skeep[t]);
    for (int r = tid; r < V; r += TPB) {
      if ((skeep[r >> 5] >> (r & 31)) & 1u) {
        int slot = __popc(skeep[r >> 5] & ((1u << (r & 31)) - 1u));
        for (int t = 0; t < (r >> 5); ++t) slot += __popc(skeep[t]);
        if (slot < DET) {
          float sv = scsS[g4 * P_ + r];
          int flat = cls * P_ + r;
          cand[g4 * DET + slot] = ((u64)f2o(sv) << 32) | (u32)(~(u32)flat);
          int so = g4 * P_ + r;
          float* rr = rec + (size_t)(g4 * DET + slot) * 12;
          rr[0] = fminf(fmaxf(aabbS[so * 4 + 0], 0.f), 1023.0f);
          rr[1] = fminf(fmaxf(aabbS[so * 4 + 1], 0.f), 799.0f);
          rr[2] = fminf(fmaxf(aabbS[so * 4 + 2], 0.f), 1023.0f);
          rr[3] = fminf(fmaxf(aabbS[so * 4 + 3], 0.f), 799.0f);
          rr[4] = pr5S[so * 5 + 0]; rr[5] = pr5S[so * 5 + 1]; rr[6] = pr5S[so * 5 + 2];
          rr[7] = pr5S[so * 5 + 3]; rr[8] = pr5S[so * 5 + 4];
          rr[9] = sv;
          rr[10] = (float)(cls + 1);
          rr[11] = 0.f;
        }
      }
    }
    int fill = tot < DET ? tot : DET;
    for (int s = fill + tid; s < DET; s += TPB) cand[g4 * DET + s] = 0ull;
  }
  __threadfence();
  grid.sync();

  // ===== Phase 5: per-image top-100 by binary-search rank (blocks 0..15) ===
  if (blockIdx.x < 16) {
    u64* lc = shbuf;                       // 2000 u64 = 16 KB
    int* ncand = (int*)(shbuf + NC);
    int b5 = blockIdx.x >> 3;              // 8 blocks per image
    int cbase = (blockIdx.x & 7) * TPB;
    if (tid == 0) *ncand = 0;
    __syncthreads();
    int nz = 0;
    for (int i = tid; i < NC; i += TPB) {
      u64 v = cand[b5 * NC + i];
      lc[i] = v;
      nz += (v != 0ull) ? 1 : 0;
    }
    if (nz > 0) atomicAdd(ncand, nz);
    __syncthreads();
    int nc = *ncand;
    if ((blockIdx.x & 7) == 0 && tid < DET && tid >= nc) {
      int o_bb = (b5 * DET + tid) * 4;
      int o_rr = B_ * DET * 4 + (b5 * DET + tid) * 5;
      int o_sc = B_ * DET * 9 + b5 * DET + tid;
      int o_lab = B_ * DET * 10 + b5 * DET + tid;
      out[o_bb + 0] = 0.f; out[o_bb + 1] = 0.f; out[o_bb + 2] = 0.f; out[o_bb + 3] = 0.f;
      out[o_rr + 0] = 0.f; out[o_rr + 1] = 0.f; out[o_rr + 2] = 0.f;
      out[o_rr + 3] = 0.f; out[o_rr + 4] = 0.f;
      out[o_sc] = 0.f;
      out[o_lab] = 0.f;
    }
    int ci = cbase + tid;
    if (ci < NC) {
      u64 k = lc[ci];
      if (k != 0ull) {
        int rank = 0;
        #pragma unroll
        for (int gp = 0; gp < CF; ++gp) {
          int lo = 0, hi = DET;
          while (lo < hi) {        // first idx with lc[gp*DET+idx] <= k (desc)
            int mid = (lo + hi) >> 1;
            if (lc[gp * DET + mid] > k) lo = mid + 1; else hi = mid;
          }
          rank += lo;
        }
        if (rank < DET) {
          const float* rr = rec + (size_t)(b5 * NC + ci) * 12;
          int o_bb = (b5 * DET + rank) * 4;
          int o_rr = B_ * DET * 4 + (b5 * DET + rank) * 5;
          int o_sc = B_ * DET * 9 + b5 * DET + rank;
          int o_lab = B_ * DET * 10 + b5 * DET + rank;
          out[o_bb + 0] = rr[0]; out[o_bb + 1] = rr[1];
          out[o_bb + 2] = rr[2]; out[o_bb + 3] = rr[3];
          out[o_rr + 0] = rr[4]; out[o_rr + 1] = rr[5]; out[o_rr + 2] = rr[6];
          out[o_rr + 3] = rr[7]; out[o_rr + 4] = rr[8];
          out[o_sc] = rr[9];
          out[o_lab] = rr[10];
        }
      }
    }
  }
}

// ---------------------------------------------------------------------------
extern "C" void kernel_launch(void* const* d_in, const int* in_sizes, int n_in,
                              void* d_out, int out_size, void* d_ws, size_t ws_size,
                              hipStream_t stream) {
  const float* logits = (const float*)d_in[0];
  const float* breg   = (const float*)d_in[1];
  const float* rrects = (const float*)d_in[2];
  float* out = (float*)d_out;

  u64*   sup   = (u64*)d_ws;                         // G*P*8 u64
  u64*   cand  = sup + (size_t)G_ * P_ * 8;          // G*DET u64
  u64*   lkeyG = cand + G_ * DET;                    // G*P u64
  int*   gV    = (int*)(lkeyG + (size_t)G_ * P_);    // 64 ints
  float* scsS  = (float*)(gV + 64);                  // G*P
  float* ptsS  = scsS + (size_t)G_ * P_;             // G*P*8
  float* aabbS = ptsS + (size_t)G_ * P_ * 8;         // G*P*4
  float* pr5S  = aabbS + (size_t)G_ * P_ * 4;        // G*P*5
  float* areaS = pr5S + (size_t)G_ * P_ * 5;         // G*P
  float* rec   = areaS + (size_t)G_ * P_;            // G*DET*12

  void* kargs[] = {
    (void*)&logits, (void*)&breg, (void*)&rrects,
    (void*)&lkeyG, (void*)&scsS, (void*)&ptsS, (void*)&aabbS, (void*)&pr5S,
    (void*)&areaS, (void*)&gV, (void*)&sup, (void*)&cand, (void*)&rec, (void*)&out
  };
  hipLaunchCooperativeKernel((const void*)fused_kernel, dim3(GRID), dim3(TPB),
                             kargs, 0, stream);
}